// Round 13
// baseline (204.725 us; speedup 1.0000x reference)
//
#include <hip/hip_runtime.h>
#include <hip/hip_bf16.h>

#define Bsz 64
#define Wln 512
#define Hd  1024
#define Vc  32000

typedef short v8s __attribute__((ext_vector_type(8)));
typedef float f32x4 __attribute__((ext_vector_type(4)));

__device__ inline unsigned short f2b(float f) {  // round to bf16
  union { float f; unsigned u; } v; v.f = f;
  return (unsigned short)((v.u + 0x8000u) >> 16);
}
__device__ inline float wave_sum(float v) {
  #pragma unroll
  for (int o = 32; o; o >>= 1) v += __shfl_down(v, o);
  return v;
}
__device__ inline float wave_max(float v) {
  #pragma unroll
  for (int o = 32; o; o >>= 1) v = fmaxf(v, __shfl_down(v, o));
  return v;
}
__device__ inline float wave_sum_all(float v) {
  #pragma unroll
  for (int o = 32; o; o >>= 1) v += __shfl_xor(v, o);
  return v;
}
__device__ inline float wave_max_all(float v) {
  #pragma unroll
  for (int o = 32; o; o >>= 1) v = fmaxf(v, __shfl_xor(v, o));
  return v;
}
__device__ inline float sigm(float x) { return 1.f / (1.f + expf(-x)); }

__device__ inline v8s cvt_frag(float4 x0, float4 x1) {
  v8s r;
  r[0] = (short)f2b(x0.x); r[1] = (short)f2b(x0.y);
  r[2] = (short)f2b(x0.z); r[3] = (short)f2b(x0.w);
  r[4] = (short)f2b(x1.x); r[5] = (short)f2b(x1.y);
  r[6] = (short)f2b(x1.z); r[7] = (short)f2b(x1.w);
  return r;
}

// stage 64 x 1024 f32 (row stride sA, optional elementwise-add Ab) -> LDS bf16, swizzled
__device__ inline void stage_A(const float* __restrict__ A, const float* __restrict__ Ab,
                               int sA, char* pool, int tid) {
  #pragma unroll
  for (int it = 0; it < 16; ++it) {
    int idx = it * 512 + tid;
    int row = idx >> 7, ch = idx & 127;
    const float* src = A + (size_t)row * sA + ch * 8;
    float4 x0 = *(const float4*)src;
    float4 x1 = *(const float4*)(src + 4);
    if (Ab) {
      const float* s2 = Ab + (size_t)row * sA + ch * 8;
      float4 y0 = *(const float4*)s2;
      float4 y1 = *(const float4*)(s2 + 4);
      x0.x += y0.x; x0.y += y0.y; x0.z += y0.z; x0.w += y0.w;
      x1.x += y1.x; x1.y += y1.y; x1.z += y1.z; x1.w += y1.w;
    }
    *(v8s*)(pool + row * 2048 + ((ch * 16) ^ ((row & 7) << 4))) = cvt_frag(x0, x1);
  }
}

// ---- single-pass flash attention: block = (b, 64-row chunk); 512 blocks ----
// Pass A: dots of rows r-1..r+6 per wave -> full[] (shifted scores + s_att).
// Block (m,S); Pass B: re-read rows (L2-hot), weighted accumulate; LDS reduce.
__global__ __launch_bounds__(512) void k_attn(
    const float* __restrict__ enc, const float* __restrict__ att_w,
    const float* __restrict__ h0, const float* __restrict__ c0,
    const float* __restrict__ att_b,
    float* __restrict__ ctxp, float* __restrict__ pm_a, float* __restrict__ ps_a)
{
  __shared__ float fullv[64];
  __shared__ float redA[8];
  __shared__ float red[8][64][17];   // 34.8 KB, conflict-free reduce
  const int b = blockIdx.x >> 3, ch = blockIdx.x & 7;
  const int tid = threadIdx.x, w = tid >> 6, lane = tid & 63;

  // s_att (redundant per 8 blocks of same b; 12 KB read)
  {
    size_t base = (size_t)(Bsz + b) * Hd;
    int j = tid * 2;
    float s = h0[base + j] * c0[base + j] * att_w[Hd + j]
            + h0[base + j + 1] * c0[base + j + 1] * att_w[Hd + j + 1];
    s = wave_sum(s);
    if (lane == 0) redA[w] = s;
  }
  __syncthreads();
  float sa = att_b[0];
  #pragma unroll
  for (int i = 0; i < 8; ++i) sa += redA[i];

  const float* aw = att_w + lane * 16;
  float4 w0 = *(const float4*)aw,       w1 = *(const float4*)(aw + 4);
  float4 w2 = *(const float4*)(aw + 8), w3 = *(const float4*)(aw + 12);
  const float* encb = enc + (size_t)b * Wln * Hd;
  const int r = ch * 64 + w * 8;       // first weight-row of this wave

  // ---- pass A: full[r+k] = (r+k==0) ? 0 : dot(enc[r+k-1]) + sa ----
  #pragma unroll
  for (int k = 0; k < 8; ++k) {
    int i = r + k;
    float v = 0.f;
    if (i > 0) {
      const float* p = encb + (size_t)(i - 1) * Hd + lane * 16;
      float4 e0 = *(const float4*)p,       e1 = *(const float4*)(p + 4);
      float4 e2 = *(const float4*)(p + 8), e3 = *(const float4*)(p + 12);
      float s = e0.x*w0.x + e0.y*w0.y + e0.z*w0.z + e0.w*w0.w
              + e1.x*w1.x + e1.y*w1.y + e1.z*w1.z + e1.w*w1.w
              + e2.x*w2.x + e2.y*w2.y + e2.z*w2.z + e2.w*w2.w
              + e3.x*w3.x + e3.y*w3.y + e3.z*w3.z + e3.w*w3.w;
      s = wave_sum(s);
      v = s + sa;
    }
    if (lane == 0) fullv[w * 8 + k] = v;
  }
  __syncthreads();

  // block-local m, S (each wave computes its own copy)
  float mv = fullv[lane];
  float M = wave_max_all(mv);
  float S = wave_sum_all(expf(mv - M));

  // ---- pass B: weighted accumulate of rows r..r+7 (L2-hot) ----
  float a[16];
  #pragma unroll
  for (int ii = 0; ii < 16; ++ii) a[ii] = 0.f;
  #pragma unroll
  for (int k = 0; k < 8; ++k) {
    float wt = expf(fullv[w * 8 + k] - M);
    const float* p = encb + (size_t)(r + k) * Hd + lane * 16;
    float4 e0 = *(const float4*)p,       e1 = *(const float4*)(p + 4);
    float4 e2 = *(const float4*)(p + 8), e3 = *(const float4*)(p + 12);
    a[0] += wt * e0.x; a[1] += wt * e0.y; a[2]  += wt * e0.z; a[3]  += wt * e0.w;
    a[4] += wt * e1.x; a[5] += wt * e1.y; a[6]  += wt * e1.z; a[7]  += wt * e1.w;
    a[8] += wt * e2.x; a[9] += wt * e2.y; a[10] += wt * e2.z; a[11] += wt * e2.w;
    a[12]+= wt * e3.x; a[13]+= wt * e3.y; a[14] += wt * e3.z; a[15] += wt * e3.w;
  }
  #pragma unroll
  for (int ii = 0; ii < 16; ++ii) red[w][lane][ii] = a[ii];
  __syncthreads();

  // cross-wave reduce: col c = lane*16 + ii
  for (int c = tid; c < Hd; c += 512) {
    float s = 0.f;
    #pragma unroll
    for (int ww = 0; ww < 8; ++ww) s += red[ww][c >> 4][c & 15];
    ctxp[((size_t)b * 8 + ch) * Hd + c] = s;
  }
  if (tid == 0) { pm_a[b * 8 + ch] = M; ps_a[b * 8 + ch] = S; }
}

// ---- combine attention partials (flash rescale) + emb gather; 64 blocks ----
__global__ __launch_bounds__(512) void k_ctx_fin(
    const float* __restrict__ ctxp, const float* __restrict__ pm_a,
    const float* __restrict__ ps_a, const int* __restrict__ input,
    const float* __restrict__ emb, float* __restrict__ cat)
{
  int b = blockIdx.x, tid = threadIdx.x;
  float Mg = pm_a[b * 8];
  #pragma unroll
  for (int c = 1; c < 8; ++c) Mg = fmaxf(Mg, pm_a[b * 8 + c]);
  float Sg = 0.f;
  float sc[8];
  #pragma unroll
  for (int c = 0; c < 8; ++c) {
    sc[c] = expf(pm_a[b * 8 + c] - Mg);
    Sg += ps_a[b * 8 + c] * sc[c];
  }
  float inv = 1.f / Sg;
  for (int h = tid; h < Hd; h += 512) {
    float s = 0.f;
    #pragma unroll
    for (int c = 0; c < 8; ++c) s += ctxp[((size_t)b * 8 + c) * Hd + h] * sc[c];
    cat[b * 2 * Hd + h] = s * inv;
  }
  int idx = input[b];
  for (int j = tid; j < Hd; j += 512)
    cat[b * 2 * Hd + Hd + j] = emb[(size_t)idx * Hd + j];
}

// ---- input half-GEMM: 128 blocks; blk<64: x1 = ctx@inW[:, :1024]^T + inb;
//      blk>=64: x2 = emb@inW[:, 1024:]^T. NS=1, KS=8, single phase. ----
__global__ __launch_bounds__(512) void k_input_gemm(
    const float* __restrict__ cat, const float* __restrict__ inW,
    const float* __restrict__ inb, float* __restrict__ x1, float* __restrict__ x2)
{
  __shared__ __align__(16) char pool[131072];
  const int tid = threadIdx.x;
  const int w = tid >> 6, lane = tid & 63;
  const int r = lane & 15, q = lane >> 4;
  const int kh = w;                       // KS=8, KSL=128
  const int half = (blockIdx.x >= 64);
  const int n0 = (blockIdx.x & 63) * 16;
  const float* A = cat + half * 1024;
  const float* B = inW + half * 1024;
  float* out = half ? x2 : x1;

  const float* bp = B + (size_t)(n0 + r) * 2048 + kh * 128 + q * 8;
  float4 breg[4][2];
  #pragma unroll
  for (int kk = 0; kk < 4; ++kk) {
    breg[kk][0] = *(const float4*)(bp + kk * 32);
    breg[kk][1] = *(const float4*)(bp + kk * 32 + 4);
  }
  stage_A(A, nullptr, 2048, pool, tid);
  __syncthreads();

  f32x4 acc[4] = {{0,0,0,0},{0,0,0,0},{0,0,0,0},{0,0,0,0}};
  const int swz = (r & 7) << 4;
  #pragma unroll
  for (int kk = 0; kk < 4; ++kk) {
    v8s bf = cvt_frag(breg[kk][0], breg[kk][1]);
    int cb = ((kh * 128 + kk * 32 + q * 8) * 2) ^ swz;
    #pragma unroll
    for (int m = 0; m < 4; ++m) {
      v8s af = *(const v8s*)(pool + (m * 16 + r) * 2048 + cb);
      acc[m] = __builtin_amdgcn_mfma_f32_16x16x32_bf16(af, bf, acc[m], 0, 0, 0);
    }
  }
  __syncthreads();

  float (*red)[64][17] = (float(*)[64][17])pool;
  #pragma unroll
  for (int m = 0; m < 4; ++m)
    #pragma unroll
    for (int rr = 0; rr < 4; ++rr)
      red[w][lane][m * 4 + rr] = acc[m][rr];
  __syncthreads();

  #pragma unroll
  for (int it = 0; it < 2; ++it) {
    int e = it * 512 + tid;                // [0,1024): 64 rows x 16 cols
    int cc = e & 15, rowi = e >> 4;
    int idx = ((rowi >> 4) << 2) + (rowi & 3);
    int le  = (((rowi >> 2) & 3) << 4) + cc;
    float s = 0.f;
    #pragma unroll
    for (int j = 0; j < 8; ++j) s += red[j][le][idx];
    float bb = half ? 0.f : inb[n0 + cc];
    out[(size_t)rowi * Hd + n0 + cc] = s + bb;
  }
}

// ---- fused gate GEMM + LSTM: 256 blocks x 16 cols (4 j x 4 gates) ----
__global__ __launch_bounds__(512) void k_gate_lstm(
    const float* __restrict__ xA, const float* __restrict__ xAb,
    const float* __restrict__ hA,
    const float* __restrict__ W_ih, const float* __restrict__ W_hh,
    const float* __restrict__ b_ih, const float* __restrict__ b_hh,
    const float* __restrict__ c0,
    float* __restrict__ out_h, float* __restrict__ out_c)
{
  __shared__ __align__(16) char pool[131072];
  const int tid = threadIdx.x;
  const int w = tid >> 6, lane = tid & 63;
  const int r = lane & 15, q = lane >> 4;
  const int kh = w;                        // NS=1: KS=8, KSL=128 per phase
  const int gate = r >> 2, jl = r & 3;
  const size_t Brow = (size_t)gate * Hd + blockIdx.x * 4 + jl;

  f32x4 acc[4] = {{0,0,0,0},{0,0,0,0},{0,0,0,0},{0,0,0,0}};
  const float* Amat[2] = { xA, hA };
  const float* Abm[2]  = { xAb, nullptr };
  const float* Wmat[2] = { W_ih, W_hh };
  #pragma unroll
  for (int p = 0; p < 2; ++p) {
    const float* bp = Wmat[p] + Brow * Hd + kh * 128 + q * 8;
    float4 breg[4][2];
    #pragma unroll
    for (int kk = 0; kk < 4; ++kk) {
      breg[kk][0] = *(const float4*)(bp + kk * 32);
      breg[kk][1] = *(const float4*)(bp + kk * 32 + 4);
    }
    stage_A(Amat[p], Abm[p], Hd, pool, tid);
    __syncthreads();
    const int swz = (r & 7) << 4;
    #pragma unroll
    for (int kk = 0; kk < 4; ++kk) {
      v8s bf = cvt_frag(breg[kk][0], breg[kk][1]);
      int cb = ((kh * 128 + kk * 32 + q * 8) * 2) ^ swz;
      #pragma unroll
      for (int m = 0; m < 4; ++m) {
        v8s af = *(const v8s*)(pool + (m * 16 + r) * 2048 + cb);
        acc[m] = __builtin_amdgcn_mfma_f32_16x16x32_bf16(af, bf, acc[m], 0, 0, 0);
      }
    }
    __syncthreads();
  }

  float (*red)[64][17] = (float(*)[64][17])pool;
  #pragma unroll
  for (int m = 0; m < 4; ++m)
    #pragma unroll
    for (int rr = 0; rr < 4; ++rr)
      red[w][lane][m * 4 + rr] = acc[m][rr];
  __syncthreads();

  if (tid < 256) {
    int b = tid >> 2, jl2 = tid & 3;
    int jg = blockIdx.x * 4 + jl2;
    float gv[4];
    #pragma unroll
    for (int g2 = 0; g2 < 4; ++g2) {
      int cc = g2 * 4 + jl2;
      int idx = ((b >> 4) << 2) + (b & 3);
      int le  = (((b >> 2) & 3) << 4) + cc;
      float s = 0.f;
      #pragma unroll
      for (int j = 0; j < 8; ++j) s += red[j][le][idx];
      gv[g2] = s + b_ih[(size_t)g2 * Hd + jg] + b_hh[(size_t)g2 * Hd + jg];
    }
    float c = sigm(gv[1]) * c0[(size_t)b * Hd + jg] + sigm(gv[0]) * tanhf(gv[2]);
    float h = sigm(gv[3]) * tanhf(c);
    out_h[(size_t)b * Hd + jg] = h;
    out_c[(size_t)b * Hd + jg] = c;
  }
}

// ---- logits GEMM + fused log-softmax partials: NS=4, 500 blocks ----
__global__ __launch_bounds__(512) void k_logits(
    const float* __restrict__ A, const float* __restrict__ B,
    const float* __restrict__ bias, float* __restrict__ out,
    float* __restrict__ pm, float* __restrict__ ps)
{
  __shared__ __align__(16) char pool[131072];
  const int tid = threadIdx.x;
  const int w = tid >> 6, lane = tid & 63;
  const int r = lane & 15, q = lane >> 4;
  const int nsub = w & 3, kh = w >> 2;    // NS=4: KS=2, KSL=512
  const int n0 = blockIdx.x * 64;

  const float* bp = B + (size_t)(n0 + nsub * 16 + r) * Hd + kh * 512 + q * 8;
  float4 breg[16][2];
  #pragma unroll
  for (int kk = 0; kk < 16; ++kk) {
    breg[kk][0] = *(const float4*)(bp + kk * 32);
    breg[kk][1] = *(const float4*)(bp + kk * 32 + 4);
  }
  stage_A(A, nullptr, Hd, pool, tid);
  __syncthreads();

  f32x4 acc[4] = {{0,0,0,0},{0,0,0,0},{0,0,0,0},{0,0,0,0}};
  const int swz = (r & 7) << 4;
  #pragma unroll
  for (int kk = 0; kk < 16; ++kk) {
    v8s bf = cvt_frag(breg[kk][0], breg[kk][1]);
    int cb = ((kh * 512 + kk * 32 + q * 8) * 2) ^ swz;
    #pragma unroll
    for (int m = 0; m < 4; ++m) {
      v8s af = *(const v8s*)(pool + (m * 16 + r) * 2048 + cb);
      acc[m] = __builtin_amdgcn_mfma_f32_16x16x32_bf16(af, bf, acc[m], 0, 0, 0);
    }
  }
  __syncthreads();

  float (*red)[64][17] = (float(*)[64][17])pool;
  #pragma unroll
  for (int m = 0; m < 4; ++m)
    #pragma unroll
    for (int rr = 0; rr < 4; ++rr)
      red[w][lane][m * 4 + rr] = acc[m][rr];
  __syncthreads();

  #pragma unroll
  for (int it = 0; it < 8; ++it) {
    int e = it * 512 + tid;               // rowi = it*8 + wave; lane = cc
    int cc = e & 63, rowi = e >> 6;
    int ns2 = cc >> 4, lo = cc & 15;
    int idx = ((rowi >> 4) << 2) + (rowi & 3);
    int le  = (((rowi >> 2) & 3) << 4) + lo;
    float val = red[ns2][le][idx] + red[ns2 + 4][le][idx] + bias[n0 + cc];
    out[(size_t)rowi * Vc + n0 + cc] = val;
    float wm = wave_max_all(val);
    float we = wave_sum_all(expf(val - wm));
    if (cc == 0) { pm[blockIdx.x * 64 + rowi] = wm; ps[blockIdx.x * 64 + rowi] = we; }
  }
}

// ---- combine 500 partials per row, subtract lse; block = (b, 8000-col chunk) ----
__global__ __launch_bounds__(512) void k_lsm_sub(
    float* __restrict__ lg, const float* __restrict__ pm, const float* __restrict__ ps)
{
  __shared__ float redA[8], redB[8];
  int b = blockIdx.x >> 2, qc = blockIdx.x & 3;
  int tid = threadIdx.x, w = tid >> 6, lane = tid & 63;
  float m = -1e30f;
  for (int j = tid; j < 500; j += 512) m = fmaxf(m, pm[j * 64 + b]);
  m = wave_max(m);
  if (lane == 0) redA[w] = m;
  __syncthreads();
  float M = redA[0];
  #pragma unroll
  for (int i = 1; i < 8; ++i) M = fmaxf(M, redA[i]);
  float s = 0.f;
  for (int j = tid; j < 500; j += 512) s += ps[j * 64 + b] * expf(pm[j * 64 + b] - M);
  s = wave_sum(s);
  if (lane == 0) redB[w] = s;
  __syncthreads();
  float S = redB[0];
  #pragma unroll
  for (int i = 1; i < 8; ++i) S += redB[i];
  float lse = M + logf(S);
  float* row = lg + (size_t)b * Vc + qc * 8000;
  for (int j = tid * 4; j < 8000; j += 2048) {
    float4 v = *(const float4*)(row + j);
    v.x -= lse; v.y -= lse; v.z -= lse; v.w -= lse;
    *(float4*)(row + j) = v;
  }
}

extern "C" void kernel_launch(void* const* d_in, const int* in_sizes, int n_in,
                              void* d_out, int out_size, void* d_ws, size_t ws_size,
                              hipStream_t stream)
{
  const int*   input = (const int*)d_in[0];
  const float* h0    = (const float*)d_in[1];
  const float* c0    = (const float*)d_in[2];
  const float* enc   = (const float*)d_in[3];
  const float* emb   = (const float*)d_in[4];
  const float* W_ih0 = (const float*)d_in[5];
  const float* W_hh0 = (const float*)d_in[6];
  const float* b_ih0 = (const float*)d_in[7];
  const float* b_hh0 = (const float*)d_in[8];
  const float* W_ih1 = (const float*)d_in[9];
  const float* W_hh1 = (const float*)d_in[10];
  const float* b_ih1 = (const float*)d_in[11];
  const float* b_hh1 = (const float*)d_in[12];
  const float* att_w = (const float*)d_in[13];
  const float* att_b = (const float*)d_in[14];
  const float* inW   = (const float*)d_in[15];
  const float* inb   = (const float*)d_in[16];
  const float* outW  = (const float*)d_in[17];
  const float* outb  = (const float*)d_in[18];
  float* out = (float*)d_out;

  char* ws = (char*)d_ws;
  float* cat    = (float*)(ws + 0);          // 64x2048 [ctx | emb]
  float* x1     = (float*)(ws + 524288);     // 64x1024
  float* x2     = (float*)(ws + 786432);     // 64x1024
  float* ctxp   = (float*)(ws + 1048576);    // 512x1024 = 2 MB
  float* pm_a   = (float*)(ws + 3145728);    // 512
  float* ps_a   = (float*)(ws + 3147776);    // 512
  float* pm     = (float*)(ws + 3149824);    // 500x64
  float* ps     = (float*)(ws + 3280896);    // 500x64

  float* out_h = out + (size_t)Bsz * Vc;     // [2,B,H]
  float* out_c = out_h + 2 * Bsz * Hd;       // [2,B,H]
  float* h1 = out_h;
  float* h2 = out_h + Bsz * Hd;

  k_attn<<<Bsz * 8, 512, 0, stream>>>(enc, att_w, h0, c0, att_b, ctxp, pm_a, ps_a);
  k_ctx_fin<<<Bsz, 512, 0, stream>>>(ctxp, pm_a, ps_a, input, emb, cat);
  k_input_gemm<<<128, 512, 0, stream>>>(cat, inW, inb, x1, x2);
  k_gate_lstm<<<256, 512, 0, stream>>>(x1, x2, h0, W_ih0, W_hh0, b_ih0, b_hh0,
                                       c0, h1, out_c);
  k_gate_lstm<<<256, 512, 0, stream>>>(h1, nullptr, h0 + (size_t)Bsz * Hd,
                                       W_ih1, W_hh1, b_ih1, b_hh1,
                                       c0 + (size_t)Bsz * Hd, h2, out_c + Bsz * Hd);
  k_logits<<<500, 512, 0, stream>>>(h2, outW, outb, out, pm, ps);
  k_lsm_sub<<<256, 512, 0, stream>>>(out, pm, ps);
}

// Round 14
// 141.455 us; speedup vs baseline: 1.4473x; 1.4473x over previous
//
#include <hip/hip_runtime.h>
#include <hip/hip_bf16.h>

#define Bsz 64
#define Wln 512
#define Hd  1024
#define Vc  32000

typedef short v8s __attribute__((ext_vector_type(8)));
typedef float f32x4 __attribute__((ext_vector_type(4)));

__device__ inline unsigned short f2b(float f) {  // round to bf16
  union { float f; unsigned u; } v; v.f = f;
  return (unsigned short)((v.u + 0x8000u) >> 16);
}
__device__ inline float wave_sum(float v) {
  #pragma unroll
  for (int o = 32; o; o >>= 1) v += __shfl_down(v, o);
  return v;
}
__device__ inline float wave_max(float v) {
  #pragma unroll
  for (int o = 32; o; o >>= 1) v = fmaxf(v, __shfl_down(v, o));
  return v;
}
__device__ inline float wave_sum_all(float v) {
  #pragma unroll
  for (int o = 32; o; o >>= 1) v += __shfl_xor(v, o);
  return v;
}
__device__ inline float wave_max_all(float v) {
  #pragma unroll
  for (int o = 32; o; o >>= 1) v = fmaxf(v, __shfl_xor(v, o));
  return v;
}
__device__ inline float sigm(float x) { return 1.f / (1.f + expf(-x)); }

__device__ inline v8s cvt_frag(float4 x0, float4 x1) {
  v8s r;
  r[0] = (short)f2b(x0.x); r[1] = (short)f2b(x0.y);
  r[2] = (short)f2b(x0.z); r[3] = (short)f2b(x0.w);
  r[4] = (short)f2b(x1.x); r[5] = (short)f2b(x1.y);
  r[6] = (short)f2b(x1.z); r[7] = (short)f2b(x1.w);
  return r;
}

// stage 64 x 1024 f32 (row stride sA, optional elementwise-add Ab) -> LDS bf16, swizzled
__device__ inline void stage_A(const float* __restrict__ A, const float* __restrict__ Ab,
                               int sA, char* pool, int tid) {
  #pragma unroll
  for (int it = 0; it < 16; ++it) {
    int idx = it * 512 + tid;
    int row = idx >> 7, ch = idx & 127;
    const float* src = A + (size_t)row * sA + ch * 8;
    float4 x0 = *(const float4*)src;
    float4 x1 = *(const float4*)(src + 4);
    if (Ab) {
      const float* s2 = Ab + (size_t)row * sA + ch * 8;
      float4 y0 = *(const float4*)s2;
      float4 y1 = *(const float4*)(s2 + 4);
      x0.x += y0.x; x0.y += y0.y; x0.z += y0.z; x0.w += y0.w;
      x1.x += y1.x; x1.y += y1.y; x1.z += y1.z; x1.w += y1.w;
    }
    *(v8s*)(pool + row * 2048 + ((ch * 16) ^ ((row & 7) << 4))) = cvt_frag(x0, x1);
  }
}

// ---- LDS-staged single-pass attention: block = (b, 32-row chunk); 1024 blocks ----
// Stage rows [c0-1, c0+32] (34 rows, 136 KB f32) once; pass A scores from LDS,
// block (m,S), pass B weighted accumulate from LDS; reduce reuses the pool.
__global__ __launch_bounds__(512) void k_attn(
    const float* __restrict__ enc, const float* __restrict__ att_w,
    const float* __restrict__ h0, const float* __restrict__ c0,
    const float* __restrict__ att_b,
    float* __restrict__ ctxp, float* __restrict__ pm_a, float* __restrict__ ps_a)
{
  __shared__ __align__(16) float pool[34 * 1024];   // 136 KB
  __shared__ float fullv[32];
  __shared__ float redA[8];
  const int b = blockIdx.x >> 4, ch = blockIdx.x & 15;
  const int c0r = ch * 32;
  const int tid = threadIdx.x, w = tid >> 6, lane = tid & 63;
  const float* encb = enc + (size_t)b * Wln * Hd;

  // stage 34 rows: slot rl <-> enc row clamp(c0r-1+rl, 0, 511)
  #pragma unroll
  for (int it = 0; it < 17; ++it) {
    int idx = it * 512 + tid;            // float4 index in [0, 8704)
    int rl = idx >> 8, c4 = idx & 255;
    int gr = c0r - 1 + rl;
    gr = gr < 0 ? 0 : (gr > Wln - 1 ? Wln - 1 : gr);
    float4 v = *(const float4*)(encb + (size_t)gr * Hd + c4 * 4);
    *(float4*)(pool + rl * 1024 + c4 * 4) = v;
  }

  // s_att (redundant per block; 12 KB)
  {
    size_t base = (size_t)(Bsz + b) * Hd;
    int j = tid * 2;
    float s = h0[base + j] * c0[base + j] * att_w[Hd + j]
            + h0[base + j + 1] * c0[base + j + 1] * att_w[Hd + j + 1];
    s = wave_sum(s);
    if (lane == 0) redA[w] = s;
  }
  __syncthreads();
  float sa = att_b[0];
  #pragma unroll
  for (int i = 0; i < 8; ++i) sa += redA[i];

  float4 aw[4];
  #pragma unroll
  for (int s4 = 0; s4 < 4; ++s4)
    aw[s4] = *(const float4*)(att_w + s4 * 256 + lane * 4);

  // ---- pass A: weight-row j = c0r + w*4 + k; score row j-1 = slot w*4+k ----
  #pragma unroll
  for (int k = 0; k < 4; ++k) {
    int lj = w * 4 + k;
    int j = c0r + lj;
    float v = 0.f;
    if (j > 0) {
      const float* rp = pool + lj * 1024;
      float s = 0.f;
      #pragma unroll
      for (int s4 = 0; s4 < 4; ++s4) {
        float4 e = *(const float4*)(rp + s4 * 256 + lane * 4);
        s += e.x * aw[s4].x + e.y * aw[s4].y + e.z * aw[s4].z + e.w * aw[s4].w;
      }
      s = wave_sum(s);
      v = s + sa;
    }
    if (lane == 0) fullv[lj] = v;
  }
  __syncthreads();

  float mv = (lane < 32) ? fullv[lane] : -1e30f;
  float M = wave_max_all(mv);
  float ev = (lane < 32) ? expf(mv - M) : 0.f;
  float S = wave_sum_all(ev);

  // ---- pass B: enc row j = slot w*4+k+1, weight exp(fullv[w*4+k]-M) ----
  float4 a4[4] = {{0,0,0,0},{0,0,0,0},{0,0,0,0},{0,0,0,0}};
  #pragma unroll
  for (int k = 0; k < 4; ++k) {
    float wt = expf(fullv[w * 4 + k] - M);
    const float* rp = pool + (w * 4 + k + 1) * 1024;
    #pragma unroll
    for (int s4 = 0; s4 < 4; ++s4) {
      float4 e = *(const float4*)(rp + s4 * 256 + lane * 4);
      a4[s4].x += wt * e.x; a4[s4].y += wt * e.y;
      a4[s4].z += wt * e.z; a4[s4].w += wt * e.w;
    }
  }
  __syncthreads();   // all pool reads done; reuse as red[8][1024]
  #pragma unroll
  for (int s4 = 0; s4 < 4; ++s4)
    *(float4*)(pool + w * 1024 + s4 * 256 + lane * 4) = a4[s4];
  __syncthreads();

  for (int c = tid; c < Hd; c += 512) {
    float s = 0.f;
    #pragma unroll
    for (int ww = 0; ww < 8; ++ww) s += pool[ww * 1024 + c];
    ctxp[(size_t)(b * 16 + ch) * Hd + c] = s;
  }
  if (tid == 0) { pm_a[b * 16 + ch] = M; ps_a[b * 16 + ch] = S; }
}

// ---- combine 16 attention partials (flash rescale) + emb gather; 64 blocks ----
__global__ __launch_bounds__(512) void k_ctx_fin(
    const float* __restrict__ ctxp, const float* __restrict__ pm_a,
    const float* __restrict__ ps_a, const int* __restrict__ input,
    const float* __restrict__ emb, float* __restrict__ cat)
{
  int b = blockIdx.x, tid = threadIdx.x;
  float Mg = pm_a[b * 16];
  #pragma unroll
  for (int c = 1; c < 16; ++c) Mg = fmaxf(Mg, pm_a[b * 16 + c]);
  float Sg = 0.f;
  float sc[16];
  #pragma unroll
  for (int c = 0; c < 16; ++c) {
    sc[c] = expf(pm_a[b * 16 + c] - Mg);
    Sg += ps_a[b * 16 + c] * sc[c];
  }
  float inv = 1.f / Sg;
  for (int h = tid; h < Hd; h += 512) {
    float s = 0.f;
    #pragma unroll
    for (int c = 0; c < 16; ++c) s += ctxp[(size_t)(b * 16 + c) * Hd + h] * sc[c];
    cat[b * 2 * Hd + h] = s * inv;
  }
  int idx = input[b];
  for (int j = tid; j < Hd; j += 512)
    cat[b * 2 * Hd + Hd + j] = emb[(size_t)idx * Hd + j];
}

// ---- input half-GEMM: 128 blocks; blk<64: x1 = ctx@inW[:, :1024]^T + inb;
//      blk>=64: x2 = emb@inW[:, 1024:]^T. NS=1, KS=8, single phase. ----
__global__ __launch_bounds__(512) void k_input_gemm(
    const float* __restrict__ cat, const float* __restrict__ inW,
    const float* __restrict__ inb, float* __restrict__ x1, float* __restrict__ x2)
{
  __shared__ __align__(16) char pool[131072];
  const int tid = threadIdx.x;
  const int w = tid >> 6, lane = tid & 63;
  const int r = lane & 15, q = lane >> 4;
  const int kh = w;                       // KS=8, KSL=128
  const int half = (blockIdx.x >= 64);
  const int n0 = (blockIdx.x & 63) * 16;
  const float* A = cat + half * 1024;
  const float* B = inW + half * 1024;
  float* out = half ? x2 : x1;

  const float* bp = B + (size_t)(n0 + r) * 2048 + kh * 128 + q * 8;
  float4 breg[4][2];
  #pragma unroll
  for (int kk = 0; kk < 4; ++kk) {
    breg[kk][0] = *(const float4*)(bp + kk * 32);
    breg[kk][1] = *(const float4*)(bp + kk * 32 + 4);
  }
  stage_A(A, nullptr, 2048, pool, tid);
  __syncthreads();

  f32x4 acc[4] = {{0,0,0,0},{0,0,0,0},{0,0,0,0},{0,0,0,0}};
  const int swz = (r & 7) << 4;
  #pragma unroll
  for (int kk = 0; kk < 4; ++kk) {
    v8s bf = cvt_frag(breg[kk][0], breg[kk][1]);
    int cb = ((kh * 128 + kk * 32 + q * 8) * 2) ^ swz;
    #pragma unroll
    for (int m = 0; m < 4; ++m) {
      v8s af = *(const v8s*)(pool + (m * 16 + r) * 2048 + cb);
      acc[m] = __builtin_amdgcn_mfma_f32_16x16x32_bf16(af, bf, acc[m], 0, 0, 0);
    }
  }
  __syncthreads();

  float (*red)[64][17] = (float(*)[64][17])pool;
  #pragma unroll
  for (int m = 0; m < 4; ++m)
    #pragma unroll
    for (int rr = 0; rr < 4; ++rr)
      red[w][lane][m * 4 + rr] = acc[m][rr];
  __syncthreads();

  #pragma unroll
  for (int it = 0; it < 2; ++it) {
    int e = it * 512 + tid;                // [0,1024): 64 rows x 16 cols
    int cc = e & 15, rowi = e >> 4;
    int idx = ((rowi >> 4) << 2) + (rowi & 3);
    int le  = (((rowi >> 2) & 3) << 4) + cc;
    float s = 0.f;
    #pragma unroll
    for (int j = 0; j < 8; ++j) s += red[j][le][idx];
    float bb = half ? 0.f : inb[n0 + cc];
    out[(size_t)rowi * Hd + n0 + cc] = s + bb;
  }
}

// ---- fused gate GEMM + LSTM: 256 blocks x 16 cols (4 j x 4 gates) ----
__global__ __launch_bounds__(512) void k_gate_lstm(
    const float* __restrict__ xA, const float* __restrict__ xAb,
    const float* __restrict__ hA,
    const float* __restrict__ W_ih, const float* __restrict__ W_hh,
    const float* __restrict__ b_ih, const float* __restrict__ b_hh,
    const float* __restrict__ c0,
    float* __restrict__ out_h, float* __restrict__ out_c)
{
  __shared__ __align__(16) char pool[131072];
  const int tid = threadIdx.x;
  const int w = tid >> 6, lane = tid & 63;
  const int r = lane & 15, q = lane >> 4;
  const int kh = w;                        // NS=1: KS=8, KSL=128 per phase
  const int gate = r >> 2, jl = r & 3;
  const size_t Brow = (size_t)gate * Hd + blockIdx.x * 4 + jl;

  f32x4 acc[4] = {{0,0,0,0},{0,0,0,0},{0,0,0,0},{0,0,0,0}};
  const float* Amat[2] = { xA, hA };
  const float* Abm[2]  = { xAb, nullptr };
  const float* Wmat[2] = { W_ih, W_hh };
  #pragma unroll
  for (int p = 0; p < 2; ++p) {
    const float* bp = Wmat[p] + Brow * Hd + kh * 128 + q * 8;
    float4 breg[4][2];
    #pragma unroll
    for (int kk = 0; kk < 4; ++kk) {
      breg[kk][0] = *(const float4*)(bp + kk * 32);
      breg[kk][1] = *(const float4*)(bp + kk * 32 + 4);
    }
    stage_A(Amat[p], Abm[p], Hd, pool, tid);
    __syncthreads();
    const int swz = (r & 7) << 4;
    #pragma unroll
    for (int kk = 0; kk < 4; ++kk) {
      v8s bf = cvt_frag(breg[kk][0], breg[kk][1]);
      int cb = ((kh * 128 + kk * 32 + q * 8) * 2) ^ swz;
      #pragma unroll
      for (int m = 0; m < 4; ++m) {
        v8s af = *(const v8s*)(pool + (m * 16 + r) * 2048 + cb);
        acc[m] = __builtin_amdgcn_mfma_f32_16x16x32_bf16(af, bf, acc[m], 0, 0, 0);
      }
    }
    __syncthreads();
  }

  float (*red)[64][17] = (float(*)[64][17])pool;
  #pragma unroll
  for (int m = 0; m < 4; ++m)
    #pragma unroll
    for (int rr = 0; rr < 4; ++rr)
      red[w][lane][m * 4 + rr] = acc[m][rr];
  __syncthreads();

  if (tid < 256) {
    int b = tid >> 2, jl2 = tid & 3;
    int jg = blockIdx.x * 4 + jl2;
    float gv[4];
    #pragma unroll
    for (int g2 = 0; g2 < 4; ++g2) {
      int cc = g2 * 4 + jl2;
      int idx = ((b >> 4) << 2) + (b & 3);
      int le  = (((b >> 2) & 3) << 4) + cc;
      float s = 0.f;
      #pragma unroll
      for (int j = 0; j < 8; ++j) s += red[j][le][idx];
      gv[g2] = s + b_ih[(size_t)g2 * Hd + jg] + b_hh[(size_t)g2 * Hd + jg];
    }
    float c = sigm(gv[1]) * c0[(size_t)b * Hd + jg] + sigm(gv[0]) * tanhf(gv[2]);
    float h = sigm(gv[3]) * tanhf(c);
    out_h[(size_t)b * Hd + jg] = h;
    out_c[(size_t)b * Hd + jg] = c;
  }
}

// ---- logits GEMM + fused log-softmax partials: NS=4, 500 blocks ----
__global__ __launch_bounds__(512) void k_logits(
    const float* __restrict__ A, const float* __restrict__ B,
    const float* __restrict__ bias, float* __restrict__ out,
    float* __restrict__ pm, float* __restrict__ ps)
{
  __shared__ __align__(16) char pool[131072];
  const int tid = threadIdx.x;
  const int w = tid >> 6, lane = tid & 63;
  const int r = lane & 15, q = lane >> 4;
  const int nsub = w & 3, kh = w >> 2;    // NS=4: KS=2, KSL=512
  const int n0 = blockIdx.x * 64;

  const float* bp = B + (size_t)(n0 + nsub * 16 + r) * Hd + kh * 512 + q * 8;
  float4 breg[16][2];
  #pragma unroll
  for (int kk = 0; kk < 16; ++kk) {
    breg[kk][0] = *(const float4*)(bp + kk * 32);
    breg[kk][1] = *(const float4*)(bp + kk * 32 + 4);
  }
  stage_A(A, nullptr, Hd, pool, tid);
  __syncthreads();

  f32x4 acc[4] = {{0,0,0,0},{0,0,0,0},{0,0,0,0},{0,0,0,0}};
  const int swz = (r & 7) << 4;
  #pragma unroll
  for (int kk = 0; kk < 16; ++kk) {
    v8s bf = cvt_frag(breg[kk][0], breg[kk][1]);
    int cb = ((kh * 512 + kk * 32 + q * 8) * 2) ^ swz;
    #pragma unroll
    for (int m = 0; m < 4; ++m) {
      v8s af = *(const v8s*)(pool + (m * 16 + r) * 2048 + cb);
      acc[m] = __builtin_amdgcn_mfma_f32_16x16x32_bf16(af, bf, acc[m], 0, 0, 0);
    }
  }
  __syncthreads();

  float (*red)[64][17] = (float(*)[64][17])pool;
  #pragma unroll
  for (int m = 0; m < 4; ++m)
    #pragma unroll
    for (int rr = 0; rr < 4; ++rr)
      red[w][lane][m * 4 + rr] = acc[m][rr];
  __syncthreads();

  #pragma unroll
  for (int it = 0; it < 8; ++it) {
    int e = it * 512 + tid;               // rowi = it*8 + wave; lane = cc
    int cc = e & 63, rowi = e >> 6;
    int ns2 = cc >> 4, lo = cc & 15;
    int idx = ((rowi >> 4) << 2) + (rowi & 3);
    int le  = (((rowi >> 2) & 3) << 4) + lo;
    float val = red[ns2][le][idx] + red[ns2 + 4][le][idx] + bias[n0 + cc];
    out[(size_t)rowi * Vc + n0 + cc] = val;
    float wm = wave_max_all(val);
    float we = wave_sum_all(expf(val - wm));
    if (cc == 0) { pm[blockIdx.x * 64 + rowi] = wm; ps[blockIdx.x * 64 + rowi] = we; }
  }
}

// ---- combine 500 partials per row, subtract lse; block = (b, 8000-col chunk) ----
__global__ __launch_bounds__(512) void k_lsm_sub(
    float* __restrict__ lg, const float* __restrict__ pm, const float* __restrict__ ps)
{
  __shared__ float redA[8], redB[8];
  int b = blockIdx.x >> 2, qc = blockIdx.x & 3;
  int tid = threadIdx.x, w = tid >> 6, lane = tid & 63;
  float m = -1e30f;
  for (int j = tid; j < 500; j += 512) m = fmaxf(m, pm[j * 64 + b]);
  m = wave_max(m);
  if (lane == 0) redA[w] = m;
  __syncthreads();
  float M = redA[0];
  #pragma unroll
  for (int i = 1; i < 8; ++i) M = fmaxf(M, redA[i]);
  float s = 0.f;
  for (int j = tid; j < 500; j += 512) s += ps[j * 64 + b] * expf(pm[j * 64 + b] - M);
  s = wave_sum(s);
  if (lane == 0) redB[w] = s;
  __syncthreads();
  float S = redB[0];
  #pragma unroll
  for (int i = 1; i < 8; ++i) S += redB[i];
  float lse = M + logf(S);
  float* row = lg + (size_t)b * Vc + qc * 8000;
  for (int j = tid * 4; j < 8000; j += 2048) {
    float4 v = *(const float4*)(row + j);
    v.x -= lse; v.y -= lse; v.z -= lse; v.w -= lse;
    *(float4*)(row + j) = v;
  }
}

extern "C" void kernel_launch(void* const* d_in, const int* in_sizes, int n_in,
                              void* d_out, int out_size, void* d_ws, size_t ws_size,
                              hipStream_t stream)
{
  const int*   input = (const int*)d_in[0];
  const float* h0    = (const float*)d_in[1];
  const float* c0    = (const float*)d_in[2];
  const float* enc   = (const float*)d_in[3];
  const float* emb   = (const float*)d_in[4];
  const float* W_ih0 = (const float*)d_in[5];
  const float* W_hh0 = (const float*)d_in[6];
  const float* b_ih0 = (const float*)d_in[7];
  const float* b_hh0 = (const float*)d_in[8];
  const float* W_ih1 = (const float*)d_in[9];
  const float* W_hh1 = (const float*)d_in[10];
  const float* b_ih1 = (const float*)d_in[11];
  const float* b_hh1 = (const float*)d_in[12];
  const float* att_w = (const float*)d_in[13];
  const float* att_b = (const float*)d_in[14];
  const float* inW   = (const float*)d_in[15];
  const float* inb   = (const float*)d_in[16];
  const float* outW  = (const float*)d_in[17];
  const float* outb  = (const float*)d_in[18];
  float* out = (float*)d_out;

  char* ws = (char*)d_ws;
  float* cat    = (float*)(ws + 0);          // 64x2048 [ctx | emb]
  float* x1     = (float*)(ws + 524288);     // 64x1024
  float* x2     = (float*)(ws + 786432);     // 64x1024
  float* ctxp   = (float*)(ws + 1048576);    // 64x16x1024 = 4 MB
  float* pm_a   = (float*)(ws + 5242880);    // 1024
  float* ps_a   = (float*)(ws + 5246976);    // 1024
  float* pm     = (float*)(ws + 5251072);    // 500x64
  float* ps     = (float*)(ws + 5382144);    // 500x64

  float* out_h = out + (size_t)Bsz * Vc;     // [2,B,H]
  float* out_c = out_h + 2 * Bsz * Hd;       // [2,B,H]
  float* h1 = out_h;
  float* h2 = out_h + Bsz * Hd;

  k_attn<<<Bsz * 16, 512, 0, stream>>>(enc, att_w, h0, c0, att_b, ctxp, pm_a, ps_a);
  k_ctx_fin<<<Bsz, 512, 0, stream>>>(ctxp, pm_a, ps_a, input, emb, cat);
  k_input_gemm<<<128, 512, 0, stream>>>(cat, inW, inb, x1, x2);
  k_gate_lstm<<<256, 512, 0, stream>>>(x1, x2, h0, W_ih0, W_hh0, b_ih0, b_hh0,
                                       c0, h1, out_c);
  k_gate_lstm<<<256, 512, 0, stream>>>(h1, nullptr, h0 + (size_t)Bsz * Hd,
                                       W_ih1, W_hh1, b_ih1, b_hh1,
                                       c0 + (size_t)Bsz * Hd, h2, out_c + Bsz * Hd);
  k_logits<<<500, 512, 0, stream>>>(h2, outW, outb, out, pm, ps);
  k_lsm_sub<<<256, 512, 0, stream>>>(out, pm, ps);
}